// Round 1
// baseline (3666.615 us; speedup 1.0000x reference)
//
#include <hip/hip_runtime.h>
#include <hip/hip_bf16.h>

// Problem constants
#define B_   8
#define S_   32
#define N_   1024
#define F_   4
#define H_   128
#define NH_  131072     // N_*H_
#define BN_  8192       // B_*N_

typedef float f32;

__device__ __forceinline__ float sigf(float x){ return 1.0f/(1.0f+__expf(-x)); }
__device__ __forceinline__ float tanhff(float x){
    float e = __expf(-2.0f*fabsf(x));
    float t = (1.0f-e)/(1.0f+e);
    return x>=0.f ? t : -t;
}

// ---------------- zero ----------------
__global__ void kzero(f32* __restrict__ p, int n){
    int i = blockIdx.x*blockDim.x + threadIdx.x;
    int stride = gridDim.x*blockDim.x;
    for(; i<n; i+=stride) p[i] = 0.f;
}

// ---------------- weight prep ----------------
// Wz[c][j] (128x512) = [W1[4+c][:384] | W2[4+c][:128]]
// Wx[f][j] (4x512), bias512[j] = [b1|b2]
// WihT/WhhT[k][j] (128x512) = W[j][k],  biasP = b_ih + b_hh
__global__ void kprep(const f32* __restrict__ W1, const f32* __restrict__ b1,
                      const f32* __restrict__ W2, const f32* __restrict__ b2,
                      const f32* __restrict__ Wih, const f32* __restrict__ Whh,
                      const f32* __restrict__ bih, const f32* __restrict__ bhh,
                      f32* __restrict__ Wz, f32* __restrict__ Wx, f32* __restrict__ bias512,
                      f32* __restrict__ WihT, f32* __restrict__ WhhT, f32* __restrict__ biasP)
{
    int i = blockIdx.x*blockDim.x + threadIdx.x;
    if(i < 128*512){
        int c = i>>9, j = i&511;
        Wz[i]   = (j<384) ? W1[(4+c)*384 + j] : W2[(4+c)*128 + (j-384)];
        int k = c;
        WihT[i] = Wih[j*128 + k];
        WhhT[i] = Whh[j*128 + k];
    }
    if(i < 4*512){
        int f = i>>9, j = i&511;
        Wx[i] = (j<384) ? W1[f*384 + j] : W2[f*128 + (j-384)];
    }
    if(i < 512){
        bias512[i] = (i<384) ? b1[i] : b2[i-384];
        biasP[i]   = bih[i] + bhh[i];
    }
}

// ---------------- x transpose:  Xr[m][(t*8+b)*4+f] = x[b][t][m][f] ----------------
__global__ void ktransx(const f32* __restrict__ x, f32* __restrict__ Xr){
    int o = blockIdx.x*blockDim.x + threadIdx.x;   // < 1048576
    int m = o>>10, q = o&1023;
    int t = q>>5, b = (q>>2)&7, f = q&3;
    Xr[o] = x[(((b<<5)|t)<<12) + (m<<2) + f];
}

// ---------------- fp32 tiled GEMM: C = A(MxK) @ B(KxNcol), 64x64x16 tiles ----------------
// MODE 0: plain store
// MODE 1: encoder epilogue: v += bias[j] + sum_f AXP[n][(t*8+b)*4+f]*Wx[f][j]; act (sig/tanh)
// MODE 2: v += bias[j]
// MODE 3: v += D[r*Ncol + j]
template<int MODE>
__global__ __launch_bounds__(256)
void gemm64(const f32* __restrict__ A, const f32* __restrict__ Bm, f32* __restrict__ C,
            int M, int Ncol, int K, int lda, int ldb,
            const f32* __restrict__ D, const f32* __restrict__ Wx,
            const f32* __restrict__ bias, int t)
{
    __shared__ float As[16][68];   // [k][m], padded stride 68 (16B-aligned rows)
    __shared__ float Bs[16][64];   // [k][j]
    const int tid = threadIdx.x;
    const int tx = tid & 15, ty = tid >> 4;
    const int col0 = blockIdx.x*64, row0 = blockIdx.y*64;
    const int am = tid >> 2, aq = tid & 3;      // A loader: row am, k-quad aq
    const int bcol = tid & 63, bkr = tid >> 6;  // B loader: col, k-group

    float acc[4][4] = {};
    for(int k0 = 0; k0 < K; k0 += 16){
        const float4 a4 = *(const float4*)(A + (size_t)(row0+am)*lda + k0 + aq*4);
        float bv[4];
        #pragma unroll
        for(int i=0;i<4;i++) bv[i] = Bm[(size_t)(k0 + bkr*4 + i)*ldb + col0 + bcol];
        #pragma unroll
        for(int i=0;i<4;i++) As[aq*4+i][am] = ((const float*)&a4)[i];
        #pragma unroll
        for(int i=0;i<4;i++) Bs[bkr*4+i][bcol] = bv[i];
        __syncthreads();
        #pragma unroll
        for(int kk=0;kk<16;kk++){
            float4 av  = *(const float4*)&As[kk][ty*4];
            float4 bvv = *(const float4*)&Bs[kk][tx*4];
            #pragma unroll
            for(int i=0;i<4;i++)
                #pragma unroll
                for(int j=0;j<4;j++)
                    acc[i][j] += ((const float*)&av)[i] * ((const float*)&bvv)[j];
        }
        __syncthreads();
    }
    #pragma unroll
    for(int i=0;i<4;i++){
        int r = row0 + ty*4 + i;
        #pragma unroll
        for(int j=0;j<4;j++){
            int cidx = col0 + tx*4 + j;
            float v = acc[i][j];
            if(MODE==1){
                int n = r>>3, b = r&7;
                const f32* ax = D + n*1024 + (t*8+b)*4;   // D = AXP
                v += bias[cidx];
                #pragma unroll
                for(int f=0;f<4;f++) v += ax[f]*Wx[f*512 + cidx];
                v = (cidx<384) ? sigf(v) : tanhff(v);
            } else if(MODE==2){
                v += bias[cidx];
            } else if(MODE==3){
                v += D[(size_t)r*Ncol + cidx];
            }
            C[(size_t)r*Ncol + cidx] = v;
        }
    }
}

// ---------------- encoder pointwise: scrambled gates, hid update, ctx accumulation ----------------
// act rows are r = n*8+b, 512 cols (cols<384: sigmoid(pre1), cols>=384: tanh(pre2))
__global__ void kscramble(const f32* __restrict__ act, f32* __restrict__ hidN,
                          f32* __restrict__ ctx){
    int idx = blockIdx.x*blockDim.x + threadIdx.x;   // < B_*NH_
    int b = idx >> 17;
    int p = idx & (NH_-1);
    int n = p >> 7, c = p & 127;
    unsigned q1 = (unsigned)p + NH_;
    unsigned q2 = (unsigned)p + 2u*NH_;
    unsigned n1 = q1/384u, j1 = q1 - n1*384u;
    unsigned n2 = q2/384u, j2 = q2 - n2*384u;
    float ig = act[(n1*8u + b)*512u + j1];
    float og = act[(n2*8u + b)*512u + j2];
    float cs = act[((unsigned)n*8u + b)*512u + 384u + c];
    float h = og * tanhff(ig*cs);
    hidN[n*1024 + b*128 + c] = h;          // node-major layout [m][b*128+c]
    ctx[((b<<10)|n)*128 + c] += h;          // decoder-row layout [b*N+n][c]
}

// ---------------- decoder pointwise LSTM ----------------
__global__ void klstm(const f32* __restrict__ gates, f32* __restrict__ cx,
                      f32* __restrict__ hx_out){
    int idx = blockIdx.x*blockDim.x + threadIdx.x;   // < BN_*H_
    int r = idx >> 7, c = idx & 127;
    const f32* g = gates + (size_t)r*512;
    float ig = sigf(g[c]);
    float fg = sigf(g[c+128]);
    float gg = tanhff(g[c+256]);
    float og = sigf(g[c+384]);
    float cv = fg*cx[idx] + ig*gg;
    cx[idx] = cv;
    hx_out[idx] = og*tanhff(cv);
}

extern "C" void kernel_launch(void* const* d_in, const int* in_sizes, int n_in,
                              void* d_out, int out_size, void* d_ws, size_t ws_size,
                              hipStream_t stream) {
    const f32* x   = (const f32*)d_in[0];
    const f32* adj = (const f32*)d_in[1];
    const f32* W1  = (const f32*)d_in[2];
    const f32* b1  = (const f32*)d_in[3];
    const f32* W2  = (const f32*)d_in[4];
    const f32* b2  = (const f32*)d_in[5];
    const f32* Wih = (const f32*)d_in[6];
    const f32* Whh = (const f32*)d_in[7];
    const f32* bih = (const f32*)d_in[8];
    const f32* bhh = (const f32*)d_in[9];
    f32* out = (f32*)d_out;
    f32* ws  = (f32*)d_ws;

    // workspace layout (floats) — total 14,879,744 floats ≈ 59.5 MB
    f32* AXP   = ws;                  // 1048576  AXP[n][(t*8+b)*4+f]
    f32* Xr    = AXP   + 1048576;     // 1048576
    f32* hidA  = Xr    + 1048576;     // 1048576  hid, node-major
    f32* hidB  = hidA  + 1048576;     // 1048576
    f32* Z     = hidB  + 1048576;     // 1048576  rows (n*8+b) x 128
    f32* act   = Z     + 1048576;     // 4194304  rows (n*8+b) x 512
    f32* ctx   = act   + 4194304;     // 1048576  rows (b*N+n) x 128
    f32* Wz    = ctx   + 1048576;     // 65536
    f32* Wx    = Wz    + 65536;       // 2048
    f32* bias512 = Wx  + 2048;        // 512
    f32* WihT  = bias512 + 512;       // 65536
    f32* WhhT  = WihT  + 65536;       // 65536
    f32* biasP = WhhT  + 65536;       // 512
    f32* ctxA  = biasP + 512;         // 4194304
    // decoder aliases (encoder-only buffers reused)
    f32* gates = act;                 // 4194304
    f32* hxA   = Xr;                  // 1048576
    f32* hxB   = hidA;                // 1048576
    f32* cx    = hidB;                // 1048576

    const int TPB = 256;
    // init
    hipLaunchKernelGGL(kzero, dim3(2048), dim3(TPB), 0, stream, hidA, 1048576);
    hipLaunchKernelGGL(kzero, dim3(2048), dim3(TPB), 0, stream, ctx, 1048576);
    hipLaunchKernelGGL(kprep, dim3(256), dim3(TPB), 0, stream,
                       W1,b1,W2,b2,Wih,Whh,bih,bhh, Wz,Wx,bias512,WihT,WhhT,biasP);
    hipLaunchKernelGGL(ktransx, dim3(4096), dim3(TPB), 0, stream, x, Xr);

    // AXP = adj @ Xr  (1024x1024x1024)
    hipLaunchKernelGGL((gemm64<0>), dim3(16,16), dim3(TPB), 0, stream,
                       adj, Xr, AXP, 1024, 1024, 1024, 1024, 1024,
                       (const f32*)nullptr, (const f32*)nullptr, (const f32*)nullptr, 0);

    // encoder: 32 steps
    for(int t = 0; t < S_; ++t){
        f32* hcur = (t & 1) ? hidB : hidA;
        f32* hnxt = (t & 1) ? hidA : hidB;
        // Z = adj @ hid   (1024 x 1024 x 1024; cols = b*128+c)
        hipLaunchKernelGGL((gemm64<0>), dim3(16,16), dim3(TPB), 0, stream,
                           adj, hcur, Z, 1024, 1024, 1024, 1024, 1024,
                           (const f32*)nullptr, (const f32*)nullptr, (const f32*)nullptr, 0);
        // act = activation( Z @ Wz + AXP_t @ Wx + bias )   (8192 x 512 x 128)
        hipLaunchKernelGGL((gemm64<1>), dim3(8,128), dim3(TPB), 0, stream,
                           Z, Wz, act, 8192, 512, 128, 128, 512,
                           AXP, Wx, bias512, t);
        // hid update + ctx accumulation
        hipLaunchKernelGGL(kscramble, dim3(4096), dim3(TPB), 0, stream, act, hnxt, ctx);
    }

    // decoder prep
    hipLaunchKernelGGL(kzero, dim3(2048), dim3(TPB), 0, stream, hxA, 1048576);
    hipLaunchKernelGGL(kzero, dim3(2048), dim3(TPB), 0, stream, cx, 1048576);
    // ctxA = ctx @ WihT + (b_ih + b_hh)   (8192 x 512 x 128)
    hipLaunchKernelGGL((gemm64<2>), dim3(8,128), dim3(TPB), 0, stream,
                       ctx, WihT, ctxA, 8192, 512, 128, 128, 512,
                       (const f32*)nullptr, (const f32*)nullptr, biasP, 0);

    // decoder: 32 steps
    for(int s = 0; s < S_; ++s){
        f32* hin  = (s & 1) ? hxB : hxA;
        f32* hout = (s == S_-1) ? out : ((s & 1) ? hxA : hxB);
        // gates = ctxA + hx @ WhhT    (8192 x 512 x 128)
        hipLaunchKernelGGL((gemm64<3>), dim3(8,128), dim3(TPB), 0, stream,
                           hin, WhhT, gates, 8192, 512, 128, 128, 512,
                           ctxA, (const f32*)nullptr, (const f32*)nullptr, 0);
        hipLaunchKernelGGL(klstm, dim3(4096), dim3(TPB), 0, stream, gates, cx, hout);
    }
}

// Round 2
// 1777.627 us; speedup vs baseline: 2.0626x; 2.0626x over previous
//
#include <hip/hip_runtime.h>
#include <hip/hip_bf16.h>

#define B_   8
#define S_   32
#define N_   1024
#define F_   4
#define H_   128
#define NH_  131072u    // N_*H_

typedef float f32;
typedef _Float16 f16;
typedef _Float16 half8 __attribute__((ext_vector_type(8)));
typedef float f32x4 __attribute__((ext_vector_type(4)));

__device__ __forceinline__ float sigf(float x){ return 1.0f/(1.0f+__expf(-x)); }
__device__ __forceinline__ float tanhff(float x){
    float e = __expf(-2.0f*fabsf(x));
    float t = (1.0f-e)/(1.0f+e);
    return x>=0.f ? t : -t;
}

// ---------------- zero ----------------
__global__ void kzero(f32* __restrict__ p, int n){
    int i = blockIdx.x*blockDim.x + threadIdx.x;
    int stride = gridDim.x*blockDim.x;
    for(; i<n; i+=stride) p[i] = 0.f;
}

// ---------------- weight prep (fp16 + fp32 aux) ----------------
__global__ void kprep(const f32* __restrict__ adj,
                      const f32* __restrict__ W1, const f32* __restrict__ b1,
                      const f32* __restrict__ W2, const f32* __restrict__ b2,
                      const f32* __restrict__ Wih, const f32* __restrict__ Whh,
                      const f32* __restrict__ bih, const f32* __restrict__ bhh,
                      f16* __restrict__ adj16,
                      f16* __restrict__ WzT16, f16* __restrict__ Whh16,
                      f32* __restrict__ WihT, f32* __restrict__ Wx,
                      f32* __restrict__ bias512, f32* __restrict__ biasP)
{
    int i = blockIdx.x*blockDim.x + threadIdx.x;
    if(i < 1048576) adj16[i] = (f16)adj[i];
    if(i < 65536){
        int j = i>>7, c = i&127;                // WzT16[j][c] = Wz[c][j]
        WzT16[i] = (f16)((j<384) ? W1[(4+c)*384 + j] : W2[(4+c)*128 + (j-384)]);
        Whh16[i] = (f16)Whh[i];                 // Whh16[j][k] = Whh[j][k]
        int k = i>>9, jj = i&511;               // WihT[k][j] = Wih[j][k]
        WihT[i] = Wih[jj*128 + k];
    }
    if(i < 2048){
        int f = i>>9, j = i&511;
        Wx[i] = (j<384) ? W1[f*384+j] : W2[f*128+(j-384)];
    }
    if(i < 512){
        bias512[i] = (i<384) ? b1[i] : b2[i-384];
        biasP[i]   = bih[i] + bhh[i];
    }
}

// ---------------- x transpose (fp16): XrT[q][m] = x[b][t][m][f], q=(t*8+b)*4+f ----------------
__global__ void ktransx(const f32* __restrict__ x, f16* __restrict__ XrT){
    int o = blockIdx.x*blockDim.x + threadIdx.x;   // < 1048576, m fastest
    int m = o & 1023, q = o >> 10;
    int f = q & 3, b = (q>>2)&7, t = q>>5;
    XrT[o] = (f16)x[((b*32+t)<<12) + (m<<2) + f];
}

// ---------------- MFMA big GEMM: C(1024x1024) = A(1024x1024) @ Bt^T ----------------
// A row-major MxK fp16, Bt row-major NxK fp16 (i.e. B transposed). 64x64 tiles, 4 waves.
template<int F32OUT>
__global__ __launch_bounds__(256)
void mfma_big(const f16* __restrict__ A, const f16* __restrict__ Bt,
              f32* __restrict__ Cf, f16* __restrict__ Ch)
{
    const int lane = threadIdx.x & 63;
    const int wave = threadIdx.x >> 6;
    const int row0 = blockIdx.y*64 + (wave>>1)*32;
    const int col0 = blockIdx.x*64 + (wave&1)*32;
    const int lr = lane & 15;
    const int kc = lane >> 4;
    const f16* Ap = A  + (size_t)(row0 + lr)*1024 + kc*8;
    const f16* Bp = Bt + (size_t)(col0 + lr)*1024 + kc*8;

    f32x4 acc[2][2] = {};
    #pragma unroll 4
    for(int k0 = 0; k0 < 1024; k0 += 32){
        half8 a0 = *(const half8*)(Ap + k0);
        half8 a1 = *(const half8*)(Ap + k0 + 16*1024);
        half8 b0 = *(const half8*)(Bp + k0);
        half8 b1 = *(const half8*)(Bp + k0 + 16*1024);
        acc[0][0] = __builtin_amdgcn_mfma_f32_16x16x32_f16(a0, b0, acc[0][0], 0,0,0);
        acc[0][1] = __builtin_amdgcn_mfma_f32_16x16x32_f16(a0, b1, acc[0][1], 0,0,0);
        acc[1][0] = __builtin_amdgcn_mfma_f32_16x16x32_f16(a1, b0, acc[1][0], 0,0,0);
        acc[1][1] = __builtin_amdgcn_mfma_f32_16x16x32_f16(a1, b1, acc[1][1], 0,0,0);
    }
    // C/D layout: col = lane&15, row = (lane>>4)*4 + i   [verified m89/m91]
    #pragma unroll
    for(int a=0;a<2;a++)
      #pragma unroll
      for(int b=0;b<2;b++)
        #pragma unroll
        for(int i=0;i<4;i++){
            int r = row0 + a*16 + kc*4 + i;
            int c = col0 + b*16 + lr;
            if(F32OUT) Cf[(size_t)r*1024 + c] = acc[a][b][i];
            else       Ch[(size_t)r*1024 + c] = (f16)acc[a][b][i];
        }
}

// ---------------- MFMA weight GEMM: (8192x512) = A(8192x128) @ Bt^T(512x128) ----------------
// Block: 32 rows x 512 cols, 4 waves (wave = col quarter). MODE 0: encoder epilogue
// (bias + x-term + sig/tanh -> act fp32). MODE 1: decoder (+ctxA, fused LSTM pointwise).
template<int MODE>
__global__ __launch_bounds__(256)
void mfma_w(const f16* __restrict__ A, const f16* __restrict__ Bt,
            const f32* __restrict__ bias512, const f32* __restrict__ AXP,
            const f32* __restrict__ Wx, int t, f32* __restrict__ act,
            const f32* __restrict__ ctxA, f32* __restrict__ cx,
            f16* __restrict__ hx, f32* __restrict__ outF, int last)
{
    const int lane = threadIdx.x & 63;
    const int wave = threadIdx.x >> 6;
    const int r0 = blockIdx.x * 32;
    const int lr = lane & 15, kc = lane >> 4;
    const f16* Ap = A  + (size_t)(r0 + lr)*128 + kc*8;
    const f16* Bp = Bt + (size_t)(wave*128 + lr)*128 + kc*8;

    f32x4 acc[2][8] = {};
    #pragma unroll
    for(int k0 = 0; k0 < 128; k0 += 32){
        half8 a0 = *(const half8*)(Ap + k0);
        half8 a1 = *(const half8*)(Ap + k0 + 16*128);
        #pragma unroll
        for(int f=0; f<8; f++){
            half8 bf = *(const half8*)(Bp + f*16*128 + k0);
            acc[0][f] = __builtin_amdgcn_mfma_f32_16x16x32_f16(a0, bf, acc[0][f], 0,0,0);
            acc[1][f] = __builtin_amdgcn_mfma_f32_16x16x32_f16(a1, bf, acc[1][f], 0,0,0);
        }
    }

    if constexpr (MODE == 0){
        // encoder: v = acc + bias + sum_f AXP[n][(t*8+b)*4+f]*Wx[f][j]; act = sig/tanh
        #pragma unroll
        for(int a=0;a<2;a++){
            #pragma unroll
            for(int i=0;i<4;i++){
                int r = r0 + a*16 + kc*4 + i;
                int n = r>>3, b = r&7;
                f32x4 ax = *(const f32x4*)(AXP + n*1024 + (t*8+b)*4);
                #pragma unroll
                for(int f=0;f<8;f++){
                    int j = wave*128 + f*16 + lr;
                    float v = acc[a][f][i] + bias512[j]
                            + ax[0]*Wx[j] + ax[1]*Wx[512+j] + ax[2]*Wx[1024+j] + ax[3]*Wx[1536+j];
                    act[(size_t)r*512 + j] = (j<384) ? sigf(v) : tanhff(v);
                }
            }
        }
    } else {
        __shared__ float g[32][512];
        #pragma unroll
        for(int a=0;a<2;a++)
          #pragma unroll
          for(int i=0;i<4;i++){
            int rl = a*16 + kc*4 + i;
            #pragma unroll
            for(int f=0;f<8;f++){
                int j = wave*128 + f*16 + lr;
                g[rl][j] = acc[a][f][i] + ctxA[(size_t)(r0+rl)*512 + j];
            }
          }
        __syncthreads();
        #pragma unroll
        for(int it=0; it<16; it++){
            int idx = it*256 + threadIdx.x;     // 0..4095
            int row = idx >> 7, c = idx & 127;
            float ig = sigf(g[row][c]);
            float fg = sigf(g[row][c+128]);
            float gg = tanhff(g[row][c+256]);
            float og = sigf(g[row][c+384]);
            int gi = (r0+row)*128 + c;
            float cv = fg*cx[gi] + ig*gg;
            cx[gi] = cv;
            float h = og*tanhff(cv);
            hx[gi] = (f16)h;
            if(last) outF[gi] = h;
        }
    }
}

// ---------------- encoder pointwise: scramble, hidT(fp16, transposed) + ctx accum ----------------
__global__ void kscr(const f32* __restrict__ act, f16* __restrict__ hidT,
                     f32* __restrict__ ctx)
{
    int blk = blockIdx.x;            // 512 blocks
    int b  = blk >> 6;
    int n0 = (blk & 63) * 16;
    __shared__ f16 th[16][128];
    #pragma unroll
    for(int i=0;i<8;i++){
        int flat = i*256 + threadIdx.x;       // 0..2047
        int nl = flat >> 7, c = flat & 127;
        int n = n0 + nl;
        int p = n*128 + c;
        unsigned q1 = (unsigned)p + NH_, q2 = (unsigned)p + 2u*NH_;
        unsigned n1 = q1/384u, j1 = q1 - n1*384u;
        unsigned n2 = q2/384u, j2 = q2 - n2*384u;
        float ig = act[(size_t)(n1*8u + b)*512u + j1];
        float og = act[(size_t)(n2*8u + b)*512u + j2];
        float cs = act[(size_t)((unsigned)n*8u + b)*512u + 384u + c];
        float h = og * tanhff(ig*cs);
        ctx[((b<<10)|n)*128 + c] += h;
        th[nl][c] = (f16)h;
    }
    __syncthreads();
    // write 16B per thread: hidT[(b*128+c)*1024 + n0 + half*8]
    int c_o = threadIdx.x >> 1, half = threadIdx.x & 1;
    half8 v;
    #pragma unroll
    for(int j=0;j<8;j++) v[j] = th[half*8+j][c_o];
    *(half8*)(hidT + (size_t)(b*128 + c_o)*1024 + n0 + half*8) = v;
}

// ---------------- fp32 tiled GEMM (kept for ctxA only): C = A@B + biasP ----------------
__global__ __launch_bounds__(256)
void gemmCtxA(const f32* __restrict__ A, const f32* __restrict__ Bm, f32* __restrict__ C,
              const f32* __restrict__ bias)
{
    __shared__ float As[16][68];
    __shared__ float Bs[16][64];
    const int tid = threadIdx.x;
    const int tx = tid & 15, ty = tid >> 4;
    const int col0 = blockIdx.x*64, row0 = blockIdx.y*64;
    const int am = tid >> 2, aq = tid & 3;
    const int bcol = tid & 63, bkr = tid >> 6;
    const int lda = 128, ldb = 512, Ncol = 512, K = 128;

    float acc[4][4] = {};
    for(int k0 = 0; k0 < K; k0 += 16){
        const float4 a4 = *(const float4*)(A + (size_t)(row0+am)*lda + k0 + aq*4);
        float bv[4];
        #pragma unroll
        for(int i=0;i<4;i++) bv[i] = Bm[(size_t)(k0 + bkr*4 + i)*ldb + col0 + bcol];
        #pragma unroll
        for(int i=0;i<4;i++) As[aq*4+i][am] = ((const float*)&a4)[i];
        #pragma unroll
        for(int i=0;i<4;i++) Bs[bkr*4+i][bcol] = bv[i];
        __syncthreads();
        #pragma unroll
        for(int kk=0;kk<16;kk++){
            float4 av  = *(const float4*)&As[kk][ty*4];
            float4 bvv = *(const float4*)&Bs[kk][tx*4];
            #pragma unroll
            for(int i=0;i<4;i++)
                #pragma unroll
                for(int j=0;j<4;j++)
                    acc[i][j] += ((const float*)&av)[i] * ((const float*)&bvv)[j];
        }
        __syncthreads();
    }
    #pragma unroll
    for(int i=0;i<4;i++){
        int r = row0 + ty*4 + i;
        #pragma unroll
        for(int j=0;j<4;j++){
            int cidx = col0 + tx*4 + j;
            C[(size_t)r*Ncol + cidx] = acc[i][j] + bias[cidx];
        }
    }
}

extern "C" void kernel_launch(void* const* d_in, const int* in_sizes, int n_in,
                              void* d_out, int out_size, void* d_ws, size_t ws_size,
                              hipStream_t stream) {
    const f32* x   = (const f32*)d_in[0];
    const f32* adj = (const f32*)d_in[1];
    const f32* W1  = (const f32*)d_in[2];
    const f32* b1  = (const f32*)d_in[3];
    const f32* W2  = (const f32*)d_in[4];
    const f32* b2  = (const f32*)d_in[5];
    const f32* Wih = (const f32*)d_in[6];
    const f32* Whh = (const f32*)d_in[7];
    const f32* bih = (const f32*)d_in[8];
    const f32* bhh = (const f32*)d_in[9];
    f32* out = (f32*)d_out;
    f32* ws  = (f32*)d_ws;

    // workspace layout (f32 slots); first 3145728 slots are zeroed
    f32* ctx    = ws;                      // 1048576 f32
    f32* cx     = ctx   + 1048576;         // 1048576 f32
    f16* hidT   = (f16*)(cx + 1048576);    // 1048576 f16 (524288 slots)
    f16* hx     = (f16*)(cx + 1572864);    // 1048576 f16 (524288 slots)
    f32* AXP    = cx    + 2097152;         // 1048576
    f16* XrT    = (f16*)(AXP + 1048576);   // 524288 slots
    f16* adj16  = (f16*)(AXP + 1572864);   // 524288 slots
    f16* Z16    = (f16*)(AXP + 2097152);   // 524288 slots
    f32* act    = AXP   + 2621440;         // 4194304
    f32* ctxA   = act   + 4194304;         // 4194304
    f16* WzT16  = (f16*)(ctxA + 4194304);  // 32768 slots
    f16* Whh16  = (f16*)(ctxA + 4227072);  // 32768 slots
    f32* WihT   = ctxA  + 4259840;         // 65536
    f32* Wx     = WihT  + 65536;           // 2048
    f32* bias512= Wx    + 2048;            // 512
    f32* biasP  = bias512 + 512;           // 512

    const int TPB = 256;
    hipLaunchKernelGGL(kzero, dim3(2048), dim3(TPB), 0, stream, ws, 3145728);
    hipLaunchKernelGGL(kprep, dim3(4096), dim3(TPB), 0, stream,
                       adj, W1,b1,W2,b2, Wih,Whh,bih,bhh,
                       adj16, WzT16, Whh16, WihT, Wx, bias512, biasP);
    hipLaunchKernelGGL(ktransx, dim3(4096), dim3(TPB), 0, stream, x, XrT);

    // AXP = adj @ Xr (fp32 out)
    hipLaunchKernelGGL((mfma_big<1>), dim3(16,16), dim3(TPB), 0, stream,
                       adj16, XrT, AXP, (f16*)nullptr);

    // encoder
    for(int t = 0; t < S_; ++t){
        hipLaunchKernelGGL((mfma_big<0>), dim3(16,16), dim3(TPB), 0, stream,
                           adj16, hidT, (f32*)nullptr, Z16);
        hipLaunchKernelGGL((mfma_w<0>), dim3(256), dim3(TPB), 0, stream,
                           Z16, WzT16, bias512, AXP, Wx, t, act,
                           (const f32*)nullptr, (f32*)nullptr, (f16*)nullptr, (f32*)nullptr, 0);
        hipLaunchKernelGGL(kscr, dim3(512), dim3(TPB), 0, stream, act, hidT, ctx);
    }

    // ctxA = ctx @ WihT + (b_ih + b_hh)   (fp32 path, runs once)
    hipLaunchKernelGGL(gemmCtxA, dim3(8,128), dim3(TPB), 0, stream, ctx, WihT, ctxA, biasP);

    // decoder (fused LSTM epilogue, in-place hx/cx per block rows)
    for(int s = 0; s < S_; ++s){
        hipLaunchKernelGGL((mfma_w<1>), dim3(256), dim3(TPB), 0, stream,
                           hx, Whh16, (const f32*)nullptr, (const f32*)nullptr,
                           (const f32*)nullptr, 0, (f32*)nullptr,
                           ctxA, cx, hx, out, (s == S_-1) ? 1 : 0);
    }
}

// Round 5
// 1343.944 us; speedup vs baseline: 2.7282x; 1.3227x over previous
//
#include <hip/hip_runtime.h>
#include <hip/hip_bf16.h>

#define B_   8
#define S_   32
#define N_   1024
#define H_   128
#define NH_  131072u    // N_*H_

typedef float f32;
typedef _Float16 f16;
typedef _Float16 half8 __attribute__((ext_vector_type(8)));
typedef float f32x4 __attribute__((ext_vector_type(4)));
typedef float f32x16 __attribute__((ext_vector_type(16)));

__device__ __forceinline__ float sigf(float x){ return 1.0f/(1.0f+__expf(-x)); }
__device__ __forceinline__ float tanhff(float x){
    float e = __expf(-2.0f*fabsf(x));
    float t = (1.0f-e)/(1.0f+e);
    return x>=0.f ? t : -t;
}

// ---------------- zero ----------------
__global__ void kzero(f32* __restrict__ p, int n){
    int i = blockIdx.x*blockDim.x + threadIdx.x;
    int stride = gridDim.x*blockDim.x;
    for(; i<n; i+=stride) p[i] = 0.f;
}

// ---------------- weight prep ----------------
// WzX16[j][k] (512x160) = Bt of [Wz | Wx | 0] ext-K weight
// Whh16[j][k] = Whh (512x128), WihT[k][j] f32, biases
__global__ void kprep(const f32* __restrict__ adj,
                      const f32* __restrict__ W1, const f32* __restrict__ b1,
                      const f32* __restrict__ W2, const f32* __restrict__ b2,
                      const f32* __restrict__ Wih, const f32* __restrict__ Whh,
                      const f32* __restrict__ bih, const f32* __restrict__ bhh,
                      f16* __restrict__ adj16, f16* __restrict__ WzX16,
                      f16* __restrict__ Whh16, f32* __restrict__ WihT,
                      f32* __restrict__ bias512, f32* __restrict__ biasP)
{
    int i = blockIdx.x*blockDim.x + threadIdx.x;
    if(i < 1048576) adj16[i] = (f16)adj[i];
    if(i < 81920){
        int j = i/160, k = i - j*160;
        float v;
        if(k < 128)      v = (j<384) ? W1[(4+k)*384 + j] : W2[(4+k)*128 + (j-384)];
        else if(k < 132) v = (j<384) ? W1[(k-128)*384 + j] : W2[(k-128)*128 + (j-384)];
        else             v = 0.f;
        WzX16[i] = (f16)v;
    }
    if(i < 65536){
        Whh16[i] = (f16)Whh[i];
        int k = i>>9, jj = i&511;
        WihT[i] = Wih[jj*128 + k];
    }
    if(i < 512){
        bias512[i] = (i<384) ? b1[i] : b2[i-384];
        biasP[i]   = bih[i] + bhh[i];
    }
}

// ---------------- x transpose (fp16): XrT[q][m], q=(t*8+b)*4+f ----------------
__global__ void ktransx(const f32* __restrict__ x, f16* __restrict__ XrT){
    int o = blockIdx.x*blockDim.x + threadIdx.x;   // < 1048576, m fastest
    int m = o & 1023, q = o >> 10;
    int f = q & 3, b = (q>>2)&7, t = q>>5;
    XrT[o] = (f16)x[((b*32+t)<<12) + (m<<2) + f];
}

// ---------------- big GEMM: C(1024x1024) = A @ Bt^T, fp16 in, f16 out ----------------
// 512 thr = 8 waves: quadrant q=w&3 (32x32 out), k-half kh=w>>2 (in-block split-K),
// depth-8 register rotation, 32x32x16 MFMA, LDS reduce of k-halves.
// PAD=1: write into Zp (row (m*8+b)*160 + cc) and fill ax cols 128..131 from AXP16[.,t]
template<int PAD>
__global__ __launch_bounds__(512)
void kbig(const f16* __restrict__ A, const f16* __restrict__ Bt,
          f16* __restrict__ C, const f16* __restrict__ AXP16, int t)
{
    const int lane = threadIdx.x & 63;
    const int w = threadIdx.x >> 6;
    const int q = w & 3, kh = w >> 2;
    const int row0 = blockIdx.y*64, col0 = blockIdx.x*64;

    if(PAD && blockIdx.x==0){
        // ax fill for this row-tile: 512 threads -> 64 m x 8 b, 8B each
        int ml = threadIdx.x >> 3, b = threadIdx.x & 7;
        int m = row0 + ml;
        *(ushort4*)(C + (size_t)(m*8+b)*160 + 128) =
            *(const ushort4*)(AXP16 + (size_t)m*1024 + t*32 + b*4);
    }

    const int mr = row0 + (q>>1)*32 + (lane&31);
    const int nc = col0 + (q&1)*32 + (lane&31);
    const int kb = kh*512 + (lane>>5)*8;
    const f16* Ap = A  + (size_t)mr*1024 + kb;
    const f16* Bp = Bt + (size_t)nc*1024 + kb;

    half8 Ab[8], Bb[8];
    #pragma unroll
    for(int i=0;i<8;i++){
        Ab[i] = *(const half8*)(Ap + i*16);
        Bb[i] = *(const half8*)(Bp + i*16);
    }
    f32x16 acc = {};
    #pragma unroll
    for(int it=0; it<32; ++it){
        half8 av = Ab[it&7], bv = Bb[it&7];
        if(it+8 < 32){
            Ab[it&7] = *(const half8*)(Ap + (it+8)*16);
            Bb[it&7] = *(const half8*)(Bp + (it+8)*16);
        }
        acc = __builtin_amdgcn_mfma_f32_32x32x16_f16(av, bv, acc, 0,0,0);
    }

    __shared__ float red[4][32][32];   // 16 KB
    if(kh==1){
        #pragma unroll
        for(int i=0;i<16;i++){
            int r = (i&3) + 8*(i>>2) + 4*(lane>>5);
            red[q][r][lane&31] = acc[i];
        }
    }
    __syncthreads();
    if(kh==0){
        #pragma unroll
        for(int i=0;i<16;i++){
            int r = (i&3) + 8*(i>>2) + 4*(lane>>5);
            float v = acc[i] + red[q][r][lane&31];
            int m  = row0 + (q>>1)*32 + r;
            int gc = col0 + (q&1)*32 + (lane&31);
            if(PAD){
                int b = gc>>7, cc = gc&127;
                C[(size_t)(m*8+b)*160 + cc] = (f16)v;
            } else {
                C[(size_t)m*1024 + gc] = (f16)v;
            }
        }
    }
}

// ---------------- encoder act GEMM: act(8192x512) = Zp(8192x160) @ WzX16^T ----------------
__global__ __launch_bounds__(256)
void kact(const f16* __restrict__ Zp, const f16* __restrict__ WzX16,
          const f32* __restrict__ bias512, f32* __restrict__ act)
{
    const int lane = threadIdx.x & 63;
    const int w = threadIdx.x >> 6;
    const int r0 = blockIdx.x * 16;
    const int lr = lane & 15, kc = lane >> 4;
    const f16* Ap = Zp    + (size_t)(r0 + lr)*160 + kc*8;
    const f16* Bp = WzX16 + (size_t)(w*128 + lr)*160 + kc*8;

    f32x4 acc[8] = {};
    #pragma unroll
    for(int k0=0; k0<160; k0+=32){
        half8 a = *(const half8*)(Ap + k0);
        #pragma unroll
        for(int f=0; f<8; f++){
            half8 b = *(const half8*)(Bp + (size_t)f*16*160 + k0);
            acc[f] = __builtin_amdgcn_mfma_f32_16x16x32_f16(a, b, acc[f], 0,0,0);
        }
    }
    #pragma unroll
    for(int f=0; f<8; f++)
      #pragma unroll
      for(int i=0; i<4; i++){
        int r = r0 + kc*4 + i;
        int j = w*128 + f*16 + lr;
        float v = acc[f][i] + bias512[j];
        act[(size_t)r*512 + j] = (j<384) ? sigf(v) : tanhff(v);
      }
}

// ---------------- encoder pointwise: scramble -> hidT(f16, transposed) + ctx accum ----------------
__global__ void kscr(const f32* __restrict__ act, f16* __restrict__ hidT,
                     f32* __restrict__ ctx)
{
    int blk = blockIdx.x;            // 512 blocks
    int b  = blk >> 6;
    int n0 = (blk & 63) * 16;
    __shared__ f16 th[16][128];
    #pragma unroll
    for(int i=0;i<8;i++){
        int flat = i*256 + threadIdx.x;       // 0..2047
        int nl = flat >> 7, c = flat & 127;
        int n = n0 + nl;
        int p = n*128 + c;
        unsigned q1 = (unsigned)p + NH_, q2 = (unsigned)p + 2u*NH_;
        unsigned n1 = q1/384u, j1 = q1 - n1*384u;
        unsigned n2 = q2/384u, j2 = q2 - n2*384u;
        float ig = act[(size_t)(n1*8u + b)*512u + j1];
        float og = act[(size_t)(n2*8u + b)*512u + j2];
        float cs = act[(size_t)((unsigned)n*8u + b)*512u + 384u + c];
        float h = og * tanhff(ig*cs);
        ctx[((b<<10)|n)*128 + c] += h;
        th[nl][c] = (f16)h;
    }
    __syncthreads();
    int c_o = threadIdx.x >> 1, half = threadIdx.x & 1;
    half8 v;
    #pragma unroll
    for(int j=0;j<8;j++) v[j] = th[half*8+j][c_o];
    *(half8*)(hidT + (size_t)(b*128 + c_o)*1024 + n0 + half*8) = v;
}

// ---------------- fp32 tiled GEMM (ctxA only, runs once): C = ctx @ WihT + biasP ----------------
__global__ __launch_bounds__(256)
void gemmCtxA(const f32* __restrict__ A, const f32* __restrict__ Bm, f32* __restrict__ C,
              const f32* __restrict__ bias)
{
    __shared__ float As[16][68];
    __shared__ float Bs[16][64];
    const int tid = threadIdx.x;
    const int tx = tid & 15, ty = tid >> 4;
    const int col0 = blockIdx.x*64, row0 = blockIdx.y*64;
    const int am = tid >> 2, aq = tid & 3;
    const int bcol = tid & 63, bkr = tid >> 6;
    const int lda = 128, ldb = 512, Ncol = 512, K = 128;

    float acc[4][4] = {};
    for(int k0 = 0; k0 < K; k0 += 16){
        const float4 a4 = *(const float4*)(A + (size_t)(row0+am)*lda + k0 + aq*4);
        float bv[4];
        #pragma unroll
        for(int i=0;i<4;i++) bv[i] = Bm[(size_t)(k0 + bkr*4 + i)*ldb + col0 + bcol];
        #pragma unroll
        for(int i=0;i<4;i++) As[aq*4+i][am] = ((const float*)&a4)[i];
        #pragma unroll
        for(int i=0;i<4;i++) Bs[bkr*4+i][bcol] = bv[i];
        __syncthreads();
        #pragma unroll
        for(int kk=0;kk<16;kk++){
            float4 av  = *(const float4*)&As[kk][ty*4];
            float4 bvv = *(const float4*)&Bs[kk][tx*4];
            #pragma unroll
            for(int i=0;i<4;i++)
                #pragma unroll
                for(int j=0;j<4;j++)
                    acc[i][j] += ((const float*)&av)[i] * ((const float*)&bvv)[j];
        }
        __syncthreads();
    }
    #pragma unroll
    for(int i=0;i<4;i++){
        int r = row0 + ty*4 + i;
        #pragma unroll
        for(int j=0;j<4;j++){
            int cidx = col0 + tx*4 + j;
            C[(size_t)r*Ncol + cidx] = acc[i][j] + bias[cidx];
        }
    }
}

// ---------------- persistent decoder: 32 LSTM steps, block = 32 independent rows ----------------
__global__ __launch_bounds__(512)
void kdec(const f16* __restrict__ Whh16, const f32* __restrict__ ctxA,
          f32* __restrict__ out)
{
    const int lane = threadIdx.x & 63;
    const int w = threadIdx.x >> 6;
    const int r0 = blockIdx.x * 32;
    const int lr = lane & 15, kc = lane >> 4;
    const int cw = w*16 + lr;             // 0..127

    __shared__ f16 hx[32][136];           // padded rows
    {
        f16* hp = &hx[0][0];
        for(int i = threadIdx.x; i < 32*136; i += 512) hp[i] = (f16)0.f;
    }

    float ca[2][4][4];
    float cxr[2][4];
    #pragma unroll
    for(int a=0;a<2;a++)
      #pragma unroll
      for(int i=0;i<4;i++){
        int r = r0 + a*16 + kc*4 + i;
        #pragma unroll
        for(int g=0;g<4;g++)
            ca[a][g][i] = ctxA[(size_t)r*512 + g*128 + cw];
        cxr[a][i] = 0.f;
      }
    __syncthreads();

    for(int s=0; s<32; ++s){
        f32x4 acc[2][4] = {};
        #pragma unroll
        for(int k0=0; k0<128; k0+=32){
            half8 a0 = *(const half8*)&hx[lr][kc*8 + k0];
            half8 a1 = *(const half8*)&hx[16+lr][kc*8 + k0];
            #pragma unroll
            for(int g=0; g<4; ++g){
                half8 bf = *(const half8*)(Whh16 + (size_t)(g*128 + cw)*128 + kc*8 + k0);
                acc[0][g] = __builtin_amdgcn_mfma_f32_16x16x32_f16(a0, bf, acc[0][g], 0,0,0);
                acc[1][g] = __builtin_amdgcn_mfma_f32_16x16x32_f16(a1, bf, acc[1][g], 0,0,0);
            }
        }
        __syncthreads();   // all hx reads done before overwrite
        #pragma unroll
        for(int a=0;a<2;a++)
          #pragma unroll
          for(int i=0;i<4;i++){
            float ig = sigf  (acc[a][0][i] + ca[a][0][i]);
            float fg = sigf  (acc[a][1][i] + ca[a][1][i]);
            float gg = tanhff(acc[a][2][i] + ca[a][2][i]);
            float og = sigf  (acc[a][3][i] + ca[a][3][i]);
            float cv = fg*cxr[a][i] + ig*gg;
            cxr[a][i] = cv;
            float h = og*tanhff(cv);
            int rloc = a*16 + kc*4 + i;
            hx[rloc][cw] = (f16)h;
            if(s==31) out[(size_t)(r0 + rloc)*128 + cw] = h;
          }
        __syncthreads();
    }
}

extern "C" void kernel_launch(void* const* d_in, const int* in_sizes, int n_in,
                              void* d_out, int out_size, void* d_ws, size_t ws_size,
                              hipStream_t stream) {
    const f32* x   = (const f32*)d_in[0];
    const f32* adj = (const f32*)d_in[1];
    const f32* W1  = (const f32*)d_in[2];
    const f32* b1  = (const f32*)d_in[3];
    const f32* W2  = (const f32*)d_in[4];
    const f32* b2  = (const f32*)d_in[5];
    const f32* Wih = (const f32*)d_in[6];
    const f32* Whh = (const f32*)d_in[7];
    const f32* bih = (const f32*)d_in[8];
    const f32* bhh = (const f32*)d_in[9];
    f32* out = (f32*)d_out;
    f32* ws  = (f32*)d_ws;

    // workspace layout, f32 units. RULE: f16 buffer of E elements takes E/2 f32 slots.
    // ctx    1024x1024 f32           -> 1048576 slots
    // hidT   1024x1024 f16 (1048576) ->  524288 slots
    // Zp     8192x160  f16 (1310720) ->  655360 slots
    // act    8192x512  f32           -> 4194304 slots
    // ctxA   8192x512  f32           -> 4194304 slots
    // AXP16  1024x1024 f16 (1048576) ->  524288 slots
    // XrT    1024x1024 f16 (1048576) ->  524288 slots
    // adj16  1024x1024 f16 (1048576) ->  524288 slots
    // WzX16  512x160   f16 (81920)   ->   40960 slots
    // Whh16  512x128   f16 (65536)   ->   32768 slots
    // WihT   128x512   f32           ->   65536 slots
    // bias512 512 f32, biasP 512 f32
    f32* ctx    = ws;                         // [0,        1048576)
    f16* hidT   = (f16*)(ws + 1048576);       // [1048576,  1572864)
    f16* Zp     = (f16*)(ws + 1572864);       // [1572864,  2228224)
    f32* act    = ws + 2228224;               // [2228224,  6422528)
    f32* ctxA   = ws + 6422528;               // [6422528, 10616832)
    f16* AXP16  = (f16*)(ws + 10616832);      // [10616832, 11141120)
    f16* XrT    = (f16*)(ws + 11141120);      // [11141120, 11665408)
    f16* adj16  = (f16*)(ws + 11665408);      // [11665408, 12189696)
    f16* WzX16  = (f16*)(ws + 12189696);      // [12189696, 12230656)
    f16* Whh16  = (f16*)(ws + 12230656);      // [12230656, 12263424)
    f32* WihT   = ws + 12263424;              // [12263424, 12328960)
    f32* bias512= ws + 12328960;              // [12328960, 12329472)
    f32* biasP  = ws + 12329472;              // [12329472, 12329984)
    // end: 12329984 f32 = 49.3 MB

    const int TPB = 256;
    // zero: ctx + hidT + Zp (covers Zp pad cols 132..159, never rewritten)
    hipLaunchKernelGGL(kzero, dim3(2048), dim3(TPB), 0, stream, ws, 2228224);
    hipLaunchKernelGGL(kprep, dim3(4096), dim3(TPB), 0, stream,
                       adj, W1,b1,W2,b2, Wih,Whh,bih,bhh,
                       adj16, WzX16, Whh16, WihT, bias512, biasP);
    hipLaunchKernelGGL(ktransx, dim3(4096), dim3(TPB), 0, stream, x, XrT);

    // AXP16 = adj @ Xr (flat f16 out)
    hipLaunchKernelGGL((kbig<0>), dim3(16,16), dim3(512), 0, stream,
                       adj16, XrT, AXP16, (const f16*)nullptr, 0);

    // encoder
    for(int t = 0; t < S_; ++t){
        hipLaunchKernelGGL((kbig<1>), dim3(16,16), dim3(512), 0, stream,
                           adj16, hidT, Zp, AXP16, t);
        hipLaunchKernelGGL(kact, dim3(512), dim3(TPB), 0, stream,
                           Zp, WzX16, bias512, act);
        hipLaunchKernelGGL(kscr, dim3(512), dim3(TPB), 0, stream, act, hidT, ctx);
    }

    // ctxA = ctx @ WihT + (b_ih + b_hh)
    hipLaunchKernelGGL(gemmCtxA, dim3(8,128), dim3(TPB), 0, stream, ctx, WihT, ctxA, biasP);

    // decoder: one persistent kernel, 32 steps, rows independent
    hipLaunchKernelGGL(kdec, dim3(256), dim3(512), 0, stream, Whh16, ctxA, out);
}

// Round 6
// 1284.877 us; speedup vs baseline: 2.8537x; 1.0460x over previous
//
#include <hip/hip_runtime.h>
#include <hip/hip_bf16.h>

#define B_   8
#define S_   32
#define N_   1024
#define H_   128
#define NH_  131072u    // N_*H_

typedef float f32;
typedef _Float16 f16;
typedef _Float16 half8 __attribute__((ext_vector_type(8)));
typedef float f32x4 __attribute__((ext_vector_type(4)));
typedef float f32x16 __attribute__((ext_vector_type(16)));

__device__ __forceinline__ float sigf(float x){ return 1.0f/(1.0f+__expf(-x)); }
__device__ __forceinline__ float tanhff(float x){
    float e = __expf(-2.0f*fabsf(x));
    float t = (1.0f-e)/(1.0f+e);
    return x>=0.f ? t : -t;
}

// ---------------- zero ----------------
__global__ void kzero(f32* __restrict__ p, int n){
    int i = blockIdx.x*blockDim.x + threadIdx.x;
    int stride = gridDim.x*blockDim.x;
    for(; i<n; i+=stride) p[i] = 0.f;
}

// ---------------- weight prep ----------------
__global__ void kprep(const f32* __restrict__ adj,
                      const f32* __restrict__ W1, const f32* __restrict__ b1,
                      const f32* __restrict__ W2, const f32* __restrict__ b2,
                      const f32* __restrict__ Wih, const f32* __restrict__ Whh,
                      const f32* __restrict__ bih, const f32* __restrict__ bhh,
                      f16* __restrict__ adj16, f16* __restrict__ WzX16,
                      f16* __restrict__ Whh16, f32* __restrict__ WihT,
                      f32* __restrict__ bias512, f32* __restrict__ biasP)
{
    int i = blockIdx.x*blockDim.x + threadIdx.x;
    if(i < 1048576) adj16[i] = (f16)adj[i];
    if(i < 81920){
        int j = i/160, k = i - j*160;
        float v;
        if(k < 128)      v = (j<384) ? W1[(4+k)*384 + j] : W2[(4+k)*128 + (j-384)];
        else if(k < 132) v = (j<384) ? W1[(k-128)*384 + j] : W2[(k-128)*128 + (j-384)];
        else             v = 0.f;
        WzX16[i] = (f16)v;
    }
    if(i < 65536){
        Whh16[i] = (f16)Whh[i];
        int k = i>>9, jj = i&511;
        WihT[i] = Wih[jj*128 + k];
    }
    if(i < 512){
        bias512[i] = (i<384) ? b1[i] : b2[i-384];
        biasP[i]   = bih[i] + bhh[i];
    }
}

// ---------------- x transpose (fp16): XrT[q][m], q=(t*8+b)*4+f ----------------
__global__ void ktransx(const f32* __restrict__ x, f16* __restrict__ XrT){
    int o = blockIdx.x*blockDim.x + threadIdx.x;   // < 1048576, m fastest
    int m = o & 1023, q = o >> 10;
    int f = q & 3, b = (q>>2)&7, t = q>>5;
    XrT[o] = (f16)x[((b*32+t)<<12) + (m<<2) + f];
}

// ---------------- big GEMM v2: C(1024x1024) = A @ Bt^T, 32x32 tiles, split-K x4 ----------------
// grid (32,32) = 1024 blocks (4/CU), 256 thr = 4 waves. Wave w owns K quarter [w*256,(w+1)*256):
// 16 MFMAs 32x32x16, two interleaved acc chains, depth-8 prefetch. LDS reduce of 4 partials.
// PAD=1: write Zp rows (m*8+b)*160 + cc, and bx==0 blocks fill ax cols 128..131 from AXP16[.,t]
template<int PAD>
__global__ __launch_bounds__(256, 4)
void kbig(const f16* __restrict__ A, const f16* __restrict__ Bt,
          f16* __restrict__ C, const f16* __restrict__ AXP16, int t)
{
    const int lane = threadIdx.x & 63;
    const int w = threadIdx.x >> 6;          // k-quarter
    const int row0 = blockIdx.y*32, col0 = blockIdx.x*32;

    if(PAD && blockIdx.x==0){
        // ax fill: 256 threads -> 32 m x 8 b, 8B each
        int ml = threadIdx.x >> 3, b = threadIdx.x & 7;
        int m = row0 + ml;
        *(ushort4*)(C + (size_t)(m*8+b)*160 + 128) =
            *(const ushort4*)(AXP16 + (size_t)m*1024 + t*32 + b*4);
    }

    const int mr = row0 + (lane & 31);
    const int nc = col0 + (lane & 31);
    const int kb = w*256 + (lane>>5)*8;
    const f16* Ap = A  + (size_t)mr*1024 + kb;
    const f16* Bp = Bt + (size_t)nc*1024 + kb;

    half8 Ab[8], Bb[8];
    #pragma unroll
    for(int i=0;i<8;i++){
        Ab[i] = *(const half8*)(Ap + i*16);
        Bb[i] = *(const half8*)(Bp + i*16);
    }
    f32x16 acc0 = {}, acc1 = {};
    #pragma unroll
    for(int it=0; it<16; ++it){
        half8 av = Ab[it&7], bv = Bb[it&7];
        if(it < 8){
            Ab[it] = *(const half8*)(Ap + (it+8)*16);
            Bb[it] = *(const half8*)(Bp + (it+8)*16);
        }
        if(it & 1) acc1 = __builtin_amdgcn_mfma_f32_32x32x16_f16(av, bv, acc1, 0,0,0);
        else       acc0 = __builtin_amdgcn_mfma_f32_32x32x16_f16(av, bv, acc0, 0,0,0);
    }
    f32x16 acc = acc0 + acc1;

    __shared__ float red[3][32][32];   // 12 KB
    if(w > 0){
        #pragma unroll
        for(int i=0;i<16;i++){
            int r = (i&3) + 8*(i>>2) + 4*(lane>>5);
            red[w-1][r][lane&31] = acc[i];
        }
    }
    __syncthreads();
    if(w == 0){
        #pragma unroll
        for(int i=0;i<16;i++){
            int r = (i&3) + 8*(i>>2) + 4*(lane>>5);
            int c = lane & 31;
            float v = acc[i] + red[0][r][c] + red[1][r][c] + red[2][r][c];
            int m  = row0 + r;
            int gc = col0 + c;
            if(PAD){
                int b = gc>>7, cc = gc&127;
                C[(size_t)(m*8+b)*160 + cc] = (f16)v;
            } else {
                C[(size_t)m*1024 + gc] = (f16)v;
            }
        }
    }
}

// ---------------- encoder act GEMM v2: act(8192x512) = Zp(8192x160) @ WzX16^T ----------------
// grid (256,2), 256 thr = 4 waves. Block: 32 rows x 256 cols; wave = 64-col quarter.
__global__ __launch_bounds__(256)
void kact(const f16* __restrict__ Zp, const f16* __restrict__ WzX16,
          const f32* __restrict__ bias512, f32* __restrict__ act)
{
    const int lane = threadIdx.x & 63;
    const int w = threadIdx.x >> 6;
    const int r0 = blockIdx.x * 32;
    const int cbase = blockIdx.y*256 + w*64;
    const int lr = lane & 15, kc = lane >> 4;
    const f16* Ap = Zp    + (size_t)(r0 + lr)*160 + kc*8;
    const f16* Bp = WzX16 + (size_t)(cbase + lr)*160 + kc*8;

    f32x4 acc[2][4] = {};
    #pragma unroll
    for(int k0=0; k0<160; k0+=32){
        half8 a0 = *(const half8*)(Ap + k0);
        half8 a1 = *(const half8*)(Ap + 16*160 + k0);
        #pragma unroll
        for(int f=0; f<4; f++){
            half8 b = *(const half8*)(Bp + (size_t)f*16*160 + k0);
            acc[0][f] = __builtin_amdgcn_mfma_f32_16x16x32_f16(a0, b, acc[0][f], 0,0,0);
            acc[1][f] = __builtin_amdgcn_mfma_f32_16x16x32_f16(a1, b, acc[1][f], 0,0,0);
        }
    }
    #pragma unroll
    for(int a=0;a<2;a++)
      #pragma unroll
      for(int f=0; f<4; f++)
        #pragma unroll
        for(int i=0; i<4; i++){
            int r = r0 + a*16 + kc*4 + i;
            int j = cbase + f*16 + lr;
            float v = acc[a][f][i] + bias512[j];
            act[(size_t)r*512 + j] = (j<384) ? sigf(v) : tanhff(v);
        }
}

// ---------------- encoder pointwise: scramble -> hidT(f16, transposed) + ctx accum ----------------
__global__ void kscr(const f32* __restrict__ act, f16* __restrict__ hidT,
                     f32* __restrict__ ctx)
{
    int blk = blockIdx.x;            // 512 blocks
    int b  = blk >> 6;
    int n0 = (blk & 63) * 16;
    __shared__ f16 th[16][128];
    #pragma unroll
    for(int i=0;i<8;i++){
        int flat = i*256 + threadIdx.x;       // 0..2047
        int nl = flat >> 7, c = flat & 127;
        int n = n0 + nl;
        int p = n*128 + c;
        unsigned q1 = (unsigned)p + NH_, q2 = (unsigned)p + 2u*NH_;
        unsigned n1 = q1/384u, j1 = q1 - n1*384u;
        unsigned n2 = q2/384u, j2 = q2 - n2*384u;
        float ig = act[(size_t)(n1*8u + b)*512u + j1];
        float og = act[(size_t)(n2*8u + b)*512u + j2];
        float cs = act[(size_t)((unsigned)n*8u + b)*512u + 384u + c];
        float h = og * tanhff(ig*cs);
        ctx[((b<<10)|n)*128 + c] += h;
        th[nl][c] = (f16)h;
    }
    __syncthreads();
    int c_o = threadIdx.x >> 1, half = threadIdx.x & 1;
    half8 v;
    #pragma unroll
    for(int j=0;j<8;j++) v[j] = th[half*8+j][c_o];
    *(half8*)(hidT + (size_t)(b*128 + c_o)*1024 + n0 + half*8) = v;
}

// ---------------- fp32 tiled GEMM (ctxA only, runs once): C = ctx @ WihT + biasP ----------------
__global__ __launch_bounds__(256)
void gemmCtxA(const f32* __restrict__ A, const f32* __restrict__ Bm, f32* __restrict__ C,
              const f32* __restrict__ bias)
{
    __shared__ float As[16][68];
    __shared__ float Bs[16][64];
    const int tid = threadIdx.x;
    const int tx = tid & 15, ty = tid >> 4;
    const int col0 = blockIdx.x*64, row0 = blockIdx.y*64;
    const int am = tid >> 2, aq = tid & 3;
    const int bcol = tid & 63, bkr = tid >> 6;
    const int lda = 128, ldb = 512, Ncol = 512, K = 128;

    float acc[4][4] = {};
    for(int k0 = 0; k0 < K; k0 += 16){
        const float4 a4 = *(const float4*)(A + (size_t)(row0+am)*lda + k0 + aq*4);
        float bv[4];
        #pragma unroll
        for(int i=0;i<4;i++) bv[i] = Bm[(size_t)(k0 + bkr*4 + i)*ldb + col0 + bcol];
        #pragma unroll
        for(int i=0;i<4;i++) As[aq*4+i][am] = ((const float*)&a4)[i];
        #pragma unroll
        for(int i=0;i<4;i++) Bs[bkr*4+i][bcol] = bv[i];
        __syncthreads();
        #pragma unroll
        for(int kk=0;kk<16;kk++){
            float4 av  = *(const float4*)&As[kk][ty*4];
            float4 bvv = *(const float4*)&Bs[kk][tx*4];
            #pragma unroll
            for(int i=0;i<4;i++)
                #pragma unroll
                for(int j=0;j<4;j++)
                    acc[i][j] += ((const float*)&av)[i] * ((const float*)&bvv)[j];
        }
        __syncthreads();
    }
    #pragma unroll
    for(int i=0;i<4;i++){
        int r = row0 + ty*4 + i;
        #pragma unroll
        for(int j=0;j<4;j++){
            int cidx = col0 + tx*4 + j;
            C[(size_t)r*Ncol + cidx] = acc[i][j] + bias[cidx];
        }
    }
}

// ---------------- persistent decoder: 32 LSTM steps; Whh hoisted to registers ----------------
__global__ __launch_bounds__(512)
void kdec(const f16* __restrict__ Whh16, const f32* __restrict__ ctxA,
          f32* __restrict__ out)
{
    const int lane = threadIdx.x & 63;
    const int w = threadIdx.x >> 6;
    const int r0 = blockIdx.x * 32;
    const int lr = lane & 15, kc = lane >> 4;
    const int cw = w*16 + lr;             // 0..127

    __shared__ f16 hx[32][152];           // stride 152 halves: 16B-granule groups 3*lr mod 8 -> 2-way max
    {
        f16* hp = &hx[0][0];
        for(int i = threadIdx.x; i < 32*152; i += 512) hp[i] = (f16)0.f;
    }

    // Whh slice resident in registers (loop-invariant): [k-chunk][gate]
    half8 wreg[4][4];
    #pragma unroll
    for(int kk=0; kk<4; ++kk)
      #pragma unroll
      for(int g=0; g<4; ++g)
        wreg[kk][g] = *(const half8*)(Whh16 + (size_t)(g*128 + cw)*128 + kc*8 + kk*32);

    float ca[2][4][4];
    float cxr[2][4];
    #pragma unroll
    for(int a=0;a<2;a++)
      #pragma unroll
      for(int i=0;i<4;i++){
        int r = r0 + a*16 + kc*4 + i;
        #pragma unroll
        for(int g=0;g<4;g++)
            ca[a][g][i] = ctxA[(size_t)r*512 + g*128 + cw];
        cxr[a][i] = 0.f;
      }
    __syncthreads();

    for(int s=0; s<32; ++s){
        f32x4 acc[2][4] = {};
        #pragma unroll
        for(int kk=0; kk<4; ++kk){
            half8 a0 = *(const half8*)&hx[lr][kc*8 + kk*32];
            half8 a1 = *(const half8*)&hx[16+lr][kc*8 + kk*32];
            #pragma unroll
            for(int g=0; g<4; ++g){
                acc[0][g] = __builtin_amdgcn_mfma_f32_16x16x32_f16(a0, wreg[kk][g], acc[0][g], 0,0,0);
                acc[1][g] = __builtin_amdgcn_mfma_f32_16x16x32_f16(a1, wreg[kk][g], acc[1][g], 0,0,0);
            }
        }
        __syncthreads();   // all hx reads done before overwrite
        #pragma unroll
        for(int a=0;a<2;a++)
          #pragma unroll
          for(int i=0;i<4;i++){
            float ig = sigf  (acc[a][0][i] + ca[a][0][i]);
            float fg = sigf  (acc[a][1][i] + ca[a][1][i]);
            float gg = tanhff(acc[a][2][i] + ca[a][2][i]);
            float og = sigf  (acc[a][3][i] + ca[a][3][i]);
            float cv = fg*cxr[a][i] + ig*gg;
            cxr[a][i] = cv;
            float h = og*tanhff(cv);
            int rloc = a*16 + kc*4 + i;
            hx[rloc][cw] = (f16)h;
            if(s==31) out[(size_t)(r0 + rloc)*128 + cw] = h;
          }
        __syncthreads();
    }
}

extern "C" void kernel_launch(void* const* d_in, const int* in_sizes, int n_in,
                              void* d_out, int out_size, void* d_ws, size_t ws_size,
                              hipStream_t stream) {
    const f32* x   = (const f32*)d_in[0];
    const f32* adj = (const f32*)d_in[1];
    const f32* W1  = (const f32*)d_in[2];
    const f32* b1  = (const f32*)d_in[3];
    const f32* W2  = (const f32*)d_in[4];
    const f32* b2  = (const f32*)d_in[5];
    const f32* Wih = (const f32*)d_in[6];
    const f32* Whh = (const f32*)d_in[7];
    const f32* bih = (const f32*)d_in[8];
    const f32* bhh = (const f32*)d_in[9];
    f32* out = (f32*)d_out;
    f32* ws  = (f32*)d_ws;

    // workspace layout, f32 units — UNCHANGED from round 5 (verified correct).
    f32* ctx    = ws;                         // [0,        1048576)
    f16* hidT   = (f16*)(ws + 1048576);       // [1048576,  1572864)
    f16* Zp     = (f16*)(ws + 1572864);       // [1572864,  2228224)
    f32* act    = ws + 2228224;               // [2228224,  6422528)
    f32* ctxA   = ws + 6422528;               // [6422528, 10616832)
    f16* AXP16  = (f16*)(ws + 10616832);      // [10616832, 11141120)
    f16* XrT    = (f16*)(ws + 11141120);      // [11141120, 11665408)
    f16* adj16  = (f16*)(ws + 11665408);      // [11665408, 12189696)
    f16* WzX16  = (f16*)(ws + 12189696);      // [12189696, 12230656)
    f16* Whh16  = (f16*)(ws + 12230656);      // [12230656, 12263424)
    f32* WihT   = ws + 12263424;              // [12263424, 12328960)
    f32* bias512= ws + 12328960;              // [12328960, 12329472)
    f32* biasP  = ws + 12329472;              // [12329472, 12329984)
    // end: 12329984 f32 = 49.3 MB

    const int TPB = 256;
    // zero: ctx + hidT + Zp (covers Zp pad cols 132..159, never rewritten)
    hipLaunchKernelGGL(kzero, dim3(2048), dim3(TPB), 0, stream, ws, 2228224);
    hipLaunchKernelGGL(kprep, dim3(4096), dim3(TPB), 0, stream,
                       adj, W1,b1,W2,b2, Wih,Whh,bih,bhh,
                       adj16, WzX16, Whh16, WihT, bias512, biasP);
    hipLaunchKernelGGL(ktransx, dim3(4096), dim3(TPB), 0, stream, x, XrT);

    // AXP16 = adj @ Xr (flat f16 out)
    hipLaunchKernelGGL((kbig<0>), dim3(32,32), dim3(TPB), 0, stream,
                       adj16, XrT, AXP16, (const f16*)nullptr, 0);

    // encoder
    for(int t = 0; t < S_; ++t){
        hipLaunchKernelGGL((kbig<1>), dim3(32,32), dim3(TPB), 0, stream,
                           adj16, hidT, Zp, AXP16, t);
        hipLaunchKernelGGL(kact, dim3(256,2), dim3(TPB), 0, stream,
                           Zp, WzX16, bias512, act);
        hipLaunchKernelGGL(kscr, dim3(512), dim3(TPB), 0, stream, act, hidT, ctx);
    }

    // ctxA = ctx @ WihT + (b_ih + b_hh)
    hipLaunchKernelGGL(gemmCtxA, dim3(8,128), dim3(TPB), 0, stream, ctx, WihT, ctxA, biasP);

    // decoder: one persistent kernel, 32 steps, rows independent
    hipLaunchKernelGGL(kdec, dim3(256), dim3(512), 0, stream, Whh16, ctxA, out);
}

// Round 7
// 1091.435 us; speedup vs baseline: 3.3594x; 1.1772x over previous
//
#include <hip/hip_runtime.h>
#include <hip/hip_bf16.h>

#define B_   8
#define S_   32
#define N_   1024
#define H_   128
#define NH_  131072u    // N_*H_

typedef float f32;
typedef _Float16 f16;
typedef _Float16 half8 __attribute__((ext_vector_type(8)));
typedef float f32x4 __attribute__((ext_vector_type(4)));
typedef float f32x16 __attribute__((ext_vector_type(16)));

// fast activations: hardware rcp (±1 ulp) instead of full-precision divide
__device__ __forceinline__ float sig_fast(float x){
    return __builtin_amdgcn_rcpf(1.0f + __expf(-x));
}
__device__ __forceinline__ float tanh_fast(float x){
    return 1.0f - 2.0f*__builtin_amdgcn_rcpf(1.0f + __expf(2.0f*x));
}

// ---------------- zero ----------------
__global__ void kzero(f32* __restrict__ p, int n){
    int i = blockIdx.x*blockDim.x + threadIdx.x;
    int stride = gridDim.x*blockDim.x;
    for(; i<n; i+=stride) p[i] = 0.f;
}

// ---------------- weight prep ----------------
__global__ void kprep(const f32* __restrict__ adj,
                      const f32* __restrict__ W1, const f32* __restrict__ b1,
                      const f32* __restrict__ W2, const f32* __restrict__ b2,
                      const f32* __restrict__ Wih, const f32* __restrict__ Whh,
                      const f32* __restrict__ bih, const f32* __restrict__ bhh,
                      f16* __restrict__ adj16, f16* __restrict__ WzX16,
                      f16* __restrict__ Whh16, f32* __restrict__ WihT,
                      f32* __restrict__ bias512, f32* __restrict__ biasP)
{
    int i = blockIdx.x*blockDim.x + threadIdx.x;
    if(i < 1048576) adj16[i] = (f16)adj[i];
    if(i < 81920){
        int j = i/160, k = i - j*160;
        float v;
        if(k < 128)      v = (j<384) ? W1[(4+k)*384 + j] : W2[(4+k)*128 + (j-384)];
        else if(k < 132) v = (j<384) ? W1[(k-128)*384 + j] : W2[(k-128)*128 + (j-384)];
        else             v = 0.f;
        WzX16[i] = (f16)v;
    }
    if(i < 65536){
        Whh16[i] = (f16)Whh[i];
        int k = i>>9, jj = i&511;
        WihT[i] = Wih[jj*128 + k];
    }
    if(i < 512){
        bias512[i] = (i<384) ? b1[i] : b2[i-384];
        biasP[i]   = bih[i] + bhh[i];
    }
}

// ---------------- x transpose (fp16): XrT[q][m], q=(t*8+b)*4+f ----------------
__global__ void ktransx(const f32* __restrict__ x, f16* __restrict__ XrT){
    int o = blockIdx.x*blockDim.x + threadIdx.x;   // < 1048576, m fastest
    int m = o & 1023, q = o >> 10;
    int f = q & 3, b = (q>>2)&7, t = q>>5;
    XrT[o] = (f16)x[((b*32+t)<<12) + (m<<2) + f];
}

// ---------------- AXP GEMM (runs once): C(1024x1024) = adj16 @ XrT^T, flat f16 out ----------------
// 32x32 tiles, grid(32,32), 256 thr = 4 waves, split-K x4.
__global__ __launch_bounds__(256, 4)
void kbigAXP(const f16* __restrict__ A, const f16* __restrict__ Bt, f16* __restrict__ C)
{
    const int lane = threadIdx.x & 63;
    const int w = threadIdx.x >> 6;          // k-quarter
    const int row0 = blockIdx.y*32, col0 = blockIdx.x*32;

    const int mr = row0 + (lane & 31);
    const int nc = col0 + (lane & 31);
    const int kb = w*256 + (lane>>5)*8;
    const f16* Ap = A  + (size_t)mr*1024 + kb;
    const f16* Bp = Bt + (size_t)nc*1024 + kb;

    half8 Ab[8], Bb[8];
    #pragma unroll
    for(int i=0;i<8;i++){
        Ab[i] = *(const half8*)(Ap + i*16);
        Bb[i] = *(const half8*)(Bp + i*16);
    }
    f32x16 acc0 = {}, acc1 = {};
    #pragma unroll
    for(int it=0; it<16; ++it){
        half8 av = Ab[it&7], bv = Bb[it&7];
        if(it < 8){
            Ab[it] = *(const half8*)(Ap + (it+8)*16);
            Bb[it] = *(const half8*)(Bp + (it+8)*16);
        }
        if(it & 1) acc1 = __builtin_amdgcn_mfma_f32_32x32x16_f16(av, bv, acc1, 0,0,0);
        else       acc0 = __builtin_amdgcn_mfma_f32_32x32x16_f16(av, bv, acc0, 0,0,0);
    }
    f32x16 acc = acc0 + acc1;

    __shared__ float red[3][32][32];
    if(w > 0){
        #pragma unroll
        for(int i=0;i<16;i++){
            int r = (i&3) + 8*(i>>2) + 4*(lane>>5);
            red[w-1][r][lane&31] = acc[i];
        }
    }
    __syncthreads();
    if(w == 0){
        #pragma unroll
        for(int i=0;i<16;i++){
            int r = (i&3) + 8*(i>>2) + 4*(lane>>5);
            int c = lane & 31;
            float v = acc[i] + red[0][r][c] + red[1][r][c] + red[2][r][c];
            C[(size_t)(row0 + r)*1024 + col0 + c] = (f16)v;
        }
    }
}

// ---------------- fused encoder step GEMM: Z (LDS) + act ----------------
// grid (8 b, 32 mg), 512 thr = 8 waves. Per block: nodes m0..m0+31, batch b.
// Phase Z: Ztile(32m x 128c) = adj16[m rows] @ hidT[(b*128+c) rows]^T, K=1024.
//   wave: q=w&3 (32-col quarter), kh=w>>2 (512 K-half). 32 MFMAs 32x32x16 each.
//   kh=1 -> red LDS; kh=0 adds -> Zs f16 LDS [32][160] (cols 128..131 = ax from AXP16, 132..159 = 0).
// Phase act: act(32 x 512) = Zs @ WzX16^T (K=160) + bias, sig/tanh -> global f32.
__global__ __launch_bounds__(512)
void kfz(const f16* __restrict__ adj16, const f16* __restrict__ hidT,
         const f16* __restrict__ WzX16, const f16* __restrict__ AXP16,
         const f32* __restrict__ bias512, f32* __restrict__ act, int t)
{
    const int tid = threadIdx.x;
    const int lane = tid & 63;
    const int w = tid >> 6;
    const int q = w & 3, kh = w >> 2;
    const int b = blockIdx.x;          // 0..7
    const int m0 = blockIdx.y * 32;    // node group

    __shared__ float red[4][32][32];   // 16 KB
    __shared__ f16 Zs[32][160];        // 10 KB

    {   // ---- Z phase ----
        const int mr = m0 + (lane & 31);
        const int nc = b*128 + q*32 + (lane & 31);
        const int kb = kh*512 + (lane>>5)*8;
        const f16* Ap = adj16 + (size_t)mr*1024 + kb;
        const f16* Bp = hidT  + (size_t)nc*1024 + kb;

        half8 Ab[8], Bb[8];
        #pragma unroll
        for(int i=0;i<8;i++){
            Ab[i] = *(const half8*)(Ap + i*16);
            Bb[i] = *(const half8*)(Bp + i*16);
        }
        f32x16 acc0 = {}, acc1 = {};
        #pragma unroll
        for(int it=0; it<32; ++it){
            half8 av = Ab[it&7], bv = Bb[it&7];
            if(it < 24){
                Ab[it&7] = *(const half8*)(Ap + (it+8)*16);
                Bb[it&7] = *(const half8*)(Bp + (it+8)*16);
            }
            if(it & 1) acc1 = __builtin_amdgcn_mfma_f32_32x32x16_f16(av, bv, acc1, 0,0,0);
            else       acc0 = __builtin_amdgcn_mfma_f32_32x32x16_f16(av, bv, acc0, 0,0,0);
        }
        f32x16 acc = acc0 + acc1;

        if(kh == 1){
            #pragma unroll
            for(int i=0;i<16;i++){
                int r = (i&3) + 8*(i>>2) + 4*(lane>>5);
                red[q][r][lane&31] = acc[i];
            }
            int local = tid & 255;
            if(local < 128){   // ax cols 128..131
                int m = local>>2, f = local&3;
                Zs[m][128+f] = AXP16[(size_t)(m0+m)*1024 + t*32 + b*4 + f];
            }
            for(int idx = local; idx < 32*28; idx += 256){  // pad cols 132..159
                int r = idx/28, c = 132 + idx - r*28;
                Zs[r][c] = (f16)0.f;
            }
        }
        __syncthreads();
        if(kh == 0){
            #pragma unroll
            for(int i=0;i<16;i++){
                int r = (i&3) + 8*(i>>2) + 4*(lane>>5);
                int c = lane & 31;
                Zs[r][q*32 + c] = (f16)(acc[i] + red[q][r][c]);
            }
        }
        __syncthreads();
    }

    // ---- act phase ----
    const int lr = lane & 15, kc = lane >> 4;
    const int cbase = w*64;
    const f16* Bp2 = WzX16 + (size_t)(cbase + lr)*160 + kc*8;

    f32x4 acc2[2][4] = {};
    #pragma unroll
    for(int k0=0; k0<160; k0+=32){
        half8 a0 = *(const half8*)&Zs[lr][kc*8 + k0];
        half8 a1 = *(const half8*)&Zs[16+lr][kc*8 + k0];
        #pragma unroll
        for(int f=0; f<4; f++){
            half8 bb = *(const half8*)(Bp2 + (size_t)f*16*160 + k0);
            acc2[0][f] = __builtin_amdgcn_mfma_f32_16x16x32_f16(a0, bb, acc2[0][f], 0,0,0);
            acc2[1][f] = __builtin_amdgcn_mfma_f32_16x16x32_f16(a1, bb, acc2[1][f], 0,0,0);
        }
    }
    #pragma unroll
    for(int a=0;a<2;a++)
      #pragma unroll
      for(int f=0; f<4; f++)
        #pragma unroll
        for(int i=0; i<4; i++){
            int m = m0 + a*16 + kc*4 + i;
            int j = cbase + f*16 + lr;
            float v = acc2[a][f][i] + bias512[j];
            act[(size_t)(m*8+b)*512 + j] = (j<384) ? sig_fast(v) : tanh_fast(v);
        }
}

// ---------------- encoder pointwise: scramble -> hidT(f16, transposed) + ctx accum ----------------
__global__ void kscr(const f32* __restrict__ act, f16* __restrict__ hidT,
                     f32* __restrict__ ctx)
{
    int blk = blockIdx.x;            // 512 blocks
    int b  = blk >> 6;
    int n0 = (blk & 63) * 16;
    __shared__ f16 th[16][128];
    #pragma unroll
    for(int i=0;i<8;i++){
        int flat = i*256 + threadIdx.x;       // 0..2047
        int nl = flat >> 7, c = flat & 127;
        int n = n0 + nl;
        int p = n*128 + c;
        unsigned q1 = (unsigned)p + NH_, q2 = (unsigned)p + 2u*NH_;
        unsigned n1 = q1/384u, j1 = q1 - n1*384u;
        unsigned n2 = q2/384u, j2 = q2 - n2*384u;
        float ig = act[(size_t)(n1*8u + b)*512u + j1];
        float og = act[(size_t)(n2*8u + b)*512u + j2];
        float cs = act[(size_t)((unsigned)n*8u + b)*512u + 384u + c];
        float h = og * tanh_fast(ig*cs);
        ctx[((b<<10)|n)*128 + c] += h;
        th[nl][c] = (f16)h;
    }
    __syncthreads();
    int c_o = threadIdx.x >> 1, half = threadIdx.x & 1;
    half8 v;
    #pragma unroll
    for(int j=0;j<8;j++) v[j] = th[half*8+j][c_o];
    *(half8*)(hidT + (size_t)(b*128 + c_o)*1024 + n0 + half*8) = v;
}

// ---------------- fp32 tiled GEMM (ctxA only, runs once): C = ctx @ WihT + biasP ----------------
__global__ __launch_bounds__(256)
void gemmCtxA(const f32* __restrict__ A, const f32* __restrict__ Bm, f32* __restrict__ C,
              const f32* __restrict__ bias)
{
    __shared__ float As[16][68];
    __shared__ float Bs[16][64];
    const int tid = threadIdx.x;
    const int tx = tid & 15, ty = tid >> 4;
    const int col0 = blockIdx.x*64, row0 = blockIdx.y*64;
    const int am = tid >> 2, aq = tid & 3;
    const int bcol = tid & 63, bkr = tid >> 6;
    const int lda = 128, ldb = 512, Ncol = 512, K = 128;

    float acc[4][4] = {};
    for(int k0 = 0; k0 < K; k0 += 16){
        const float4 a4 = *(const float4*)(A + (size_t)(row0+am)*lda + k0 + aq*4);
        float bv[4];
        #pragma unroll
        for(int i=0;i<4;i++) bv[i] = Bm[(size_t)(k0 + bkr*4 + i)*ldb + col0 + bcol];
        #pragma unroll
        for(int i=0;i<4;i++) As[aq*4+i][am] = ((const float*)&a4)[i];
        #pragma unroll
        for(int i=0;i<4;i++) Bs[bkr*4+i][bcol] = bv[i];
        __syncthreads();
        #pragma unroll
        for(int kk=0;kk<16;kk++){
            float4 av  = *(const float4*)&As[kk][ty*4];
            float4 bvv = *(const float4*)&Bs[kk][tx*4];
            #pragma unroll
            for(int i=0;i<4;i++)
                #pragma unroll
                for(int j=0;j<4;j++)
                    acc[i][j] += ((const float*)&av)[i] * ((const float*)&bvv)[j];
        }
        __syncthreads();
    }
    #pragma unroll
    for(int i=0;i<4;i++){
        int r = row0 + ty*4 + i;
        #pragma unroll
        for(int j=0;j<4;j++){
            int cidx = col0 + tx*4 + j;
            C[(size_t)r*Ncol + cidx] = acc[i][j] + bias[cidx];
        }
    }
}

// ---------------- persistent decoder: 32 LSTM steps; Whh in registers; fast pointwise ----------------
__global__ __launch_bounds__(512)
void kdec(const f16* __restrict__ Whh16, const f32* __restrict__ ctxA,
          f32* __restrict__ out)
{
    const int lane = threadIdx.x & 63;
    const int w = threadIdx.x >> 6;
    const int r0 = blockIdx.x * 32;
    const int lr = lane & 15, kc = lane >> 4;
    const int cw = w*16 + lr;             // 0..127

    __shared__ f16 hx[32][152];
    {
        f16* hp = &hx[0][0];
        for(int i = threadIdx.x; i < 32*152; i += 512) hp[i] = (f16)0.f;
    }

    half8 wreg[4][4];
    #pragma unroll
    for(int kk=0; kk<4; ++kk)
      #pragma unroll
      for(int g=0; g<4; ++g)
        wreg[kk][g] = *(const half8*)(Whh16 + (size_t)(g*128 + cw)*128 + kc*8 + kk*32);

    float ca[2][4][4];
    float cxr[2][4];
    #pragma unroll
    for(int a=0;a<2;a++)
      #pragma unroll
      for(int i=0;i<4;i++){
        int r = r0 + a*16 + kc*4 + i;
        #pragma unroll
        for(int g=0;g<4;g++)
            ca[a][g][i] = ctxA[(size_t)r*512 + g*128 + cw];
        cxr[a][i] = 0.f;
      }
    __syncthreads();

    for(int s=0; s<32; ++s){
        f32x4 acc[2][4] = {};
        #pragma unroll
        for(int kk=0; kk<4; ++kk){
            half8 a0 = *(const half8*)&hx[lr][kc*8 + kk*32];
            half8 a1 = *(const half8*)&hx[16+lr][kc*8 + kk*32];
            #pragma unroll
            for(int g=0; g<4; ++g){
                acc[0][g] = __builtin_amdgcn_mfma_f32_16x16x32_f16(a0, wreg[kk][g], acc[0][g], 0,0,0);
                acc[1][g] = __builtin_amdgcn_mfma_f32_16x16x32_f16(a1, wreg[kk][g], acc[1][g], 0,0,0);
            }
        }
        __syncthreads();   // all hx reads done before overwrite
        #pragma unroll
        for(int a=0;a<2;a++)
          #pragma unroll
          for(int i=0;i<4;i++){
            float ig = sig_fast (acc[a][0][i] + ca[a][0][i]);
            float fg = sig_fast (acc[a][1][i] + ca[a][1][i]);
            float gg = tanh_fast(acc[a][2][i] + ca[a][2][i]);
            float og = sig_fast (acc[a][3][i] + ca[a][3][i]);
            float cv = fg*cxr[a][i] + ig*gg;
            cxr[a][i] = cv;
            float h = og*tanh_fast(cv);
            int rloc = a*16 + kc*4 + i;
            hx[rloc][cw] = (f16)h;
            if(s==31) out[(size_t)(r0 + rloc)*128 + cw] = h;
          }
        __syncthreads();
    }
}

extern "C" void kernel_launch(void* const* d_in, const int* in_sizes, int n_in,
                              void* d_out, int out_size, void* d_ws, size_t ws_size,
                              hipStream_t stream) {
    const f32* x   = (const f32*)d_in[0];
    const f32* adj = (const f32*)d_in[1];
    const f32* W1  = (const f32*)d_in[2];
    const f32* b1  = (const f32*)d_in[3];
    const f32* W2  = (const f32*)d_in[4];
    const f32* b2  = (const f32*)d_in[5];
    const f32* Wih = (const f32*)d_in[6];
    const f32* Whh = (const f32*)d_in[7];
    const f32* bih = (const f32*)d_in[8];
    const f32* bhh = (const f32*)d_in[9];
    f32* out = (f32*)d_out;
    f32* ws  = (f32*)d_ws;

    // workspace layout, f32 units — IDENTICAL to round 5/6 (verified). Zp region now unused.
    f32* ctx    = ws;                         // [0,        1048576)
    f16* hidT   = (f16*)(ws + 1048576);       // [1048576,  1572864)
    // (f16* Zp   = (f16*)(ws + 1572864);     //  unused now)
    f32* act    = ws + 2228224;               // [2228224,  6422528)
    f32* ctxA   = ws + 6422528;               // [6422528, 10616832)
    f16* AXP16  = (f16*)(ws + 10616832);      // [10616832, 11141120)
    f16* XrT    = (f16*)(ws + 11141120);      // [11141120, 11665408)
    f16* adj16  = (f16*)(ws + 11665408);      // [11665408, 12189696)
    f16* WzX16  = (f16*)(ws + 12189696);      // [12189696, 12230656)
    f16* Whh16  = (f16*)(ws + 12230656);      // [12230656, 12263424)
    f32* WihT   = ws + 12263424;              // [12263424, 12328960)
    f32* bias512= ws + 12328960;              // [12328960, 12329472)
    f32* biasP  = ws + 12329472;              // [12329472, 12329984)
    // end: 12329984 f32 = 49.3 MB

    const int TPB = 256;
    // zero: ctx + hidT
    hipLaunchKernelGGL(kzero, dim3(2048), dim3(TPB), 0, stream, ws, 1572864);
    hipLaunchKernelGGL(kprep, dim3(4096), dim3(TPB), 0, stream,
                       adj, W1,b1,W2,b2, Wih,Whh,bih,bhh,
                       adj16, WzX16, Whh16, WihT, bias512, biasP);
    hipLaunchKernelGGL(ktransx, dim3(4096), dim3(TPB), 0, stream, x, XrT);

    // AXP16 = adj @ Xr (flat f16 out)
    hipLaunchKernelGGL(kbigAXP, dim3(32,32), dim3(TPB), 0, stream, adj16, XrT, AXP16);

    // encoder: fused (Z in LDS + act) + scramble
    for(int t = 0; t < S_; ++t){
        hipLaunchKernelGGL(kfz, dim3(8,32), dim3(512), 0, stream,
                           adj16, hidT, WzX16, AXP16, bias512, act, t);
        hipLaunchKernelGGL(kscr, dim3(512), dim3(TPB), 0, stream, act, hidT, ctx);
    }

    // ctxA = ctx @ WihT + (b_ih + b_hh)
    hipLaunchKernelGGL(gemmCtxA, dim3(8,128), dim3(TPB), 0, stream, ctx, WihT, ctxA, biasP);

    // decoder: one persistent kernel, 32 steps, rows independent
    hipLaunchKernelGGL(kdec, dim3(256), dim3(512), 0, stream, Whh16, ctxA, out);
}